// Round 7
// baseline (105.778 us; speedup 1.0000x reference)
//
#include <hip/hip_runtime.h>
#include <hip/hip_bf16.h>
#include <math.h>

constexpr int BROWS = 4096;   // batch (M)
constexpr int DDIM  = 2048;   // input features (K)
constexpr int NCOMP = 4;
constexpr int DCOMP = 1024;
constexpr int NOUT  = NCOMP * DCOMP;  // 4096 output cols

typedef __attribute__((ext_vector_type(8))) short bf16x8;
typedef __attribute__((ext_vector_type(4))) float f32x4;
typedef __attribute__((ext_vector_type(4))) short s16x4;

__device__ __forceinline__ short f2bf(float f) {
  union { float f; unsigned u; } v; v.f = f;
  unsigned r = v.u + 0x7FFFu + ((v.u >> 16) & 1u);  // round-to-nearest-even
  return (short)(r >> 16);
}

#define GLOAD_LDS16(gptr, lptr) __builtin_amdgcn_global_load_lds( \
    (const __attribute__((address_space(1))) void*)(gptr),        \
    (__attribute__((address_space(3))) void*)(lptr), 16, 0, 0)

// =======================================================================
// Prep (r5-proven form): blocks [0,1024) gating (1 row/wave) + x f32->bf16;
// [1024,3072) Wc transpose+convert.
// =======================================================================
__global__ __launch_bounds__(256) void prep_kernel(
    const float* __restrict__ x, const float* __restrict__ noise,
    const float* __restrict__ Wg, const float* __restrict__ bg,
    const float* __restrict__ Wn, const float* __restrict__ bn,
    const float* __restrict__ Wc,
    float* __restrict__ Gout, short* __restrict__ xb, short* __restrict__ WcT) {
  __shared__ float tile[64][65];
  const int bid = blockIdx.x;
  const int tid = threadIdx.x;

  if (bid < 1024) {
    const int lane = tid & 63;
    const int row  = bid * 4 + (tid >> 6);
    const float* xr = x + (size_t)row * DDIM;
    short* xbr = xb + (size_t)row * DDIM;

    float ag[4] = {0.f, 0.f, 0.f, 0.f};
    float an[4] = {0.f, 0.f, 0.f, 0.f};
#pragma unroll
    for (int i = 0; i < 8; i++) {
      int d = i * 256 + lane * 4;
      float4 v = *reinterpret_cast<const float4*>(xr + d);
      s16x4 s; s.x = f2bf(v.x); s.y = f2bf(v.y); s.z = f2bf(v.z); s.w = f2bf(v.w);
      *reinterpret_cast<s16x4*>(xbr + d) = s;
      float xv[4] = {v.x, v.y, v.z, v.w};
#pragma unroll
      for (int j = 0; j < 4; j++) {
        float4 wg = *reinterpret_cast<const float4*>(Wg + 4 * (d + j));
        float4 wn = *reinterpret_cast<const float4*>(Wn + 4 * (d + j));
        ag[0] += xv[j] * wg.x; ag[1] += xv[j] * wg.y;
        ag[2] += xv[j] * wg.z; ag[3] += xv[j] * wg.w;
        an[0] += xv[j] * wn.x; an[1] += xv[j] * wn.y;
        an[2] += xv[j] * wn.z; an[3] += xv[j] * wn.w;
      }
    }
#pragma unroll
    for (int off = 32; off > 0; off >>= 1) {
#pragma unroll
      for (int c = 0; c < 4; c++) {
        ag[c] += __shfl_xor(ag[c], off);
        an[c] += __shfl_xor(an[c], off);
      }
    }
    if (lane == 0) {
      float H[4];
#pragma unroll
      for (int c = 0; c < 4; c++) {
        float v  = an[c] + bn[c];
        float sp = (v > 20.f) ? v : log1pf(expf(v));
        H[c] = (ag[c] + bg[c]) + noise[(size_t)row * NCOMP + c] * sp;
      }
      int k = 0; float best = H[0];
#pragma unroll
      for (int c = 1; c < 4; c++) { if (H[c] > best) { best = H[c]; k = c; } }
#pragma unroll
      for (int c = 0; c < 4; c++)
        Gout[(size_t)row * NCOMP + c] = (c <= k) ? 1.0f : 0.0f;
    }
  } else {
    const int tb  = bid - 1024;
    const int o_t = tb & 15, d_t = (tb >> 4) & 31, c = tb >> 9;
    const int d0 = d_t * 64, o0 = o_t * 64;
    const int col = tid & 63, rb = tid >> 6;

    const float* src = Wc + ((size_t)c * DDIM + d0) * DCOMP + o0;
#pragma unroll
    for (int i = 0; i < 16; i++) {
      int r = rb + i * 4;
      tile[r][col] = src[(size_t)r * DCOMP + col];
    }
    __syncthreads();
    short* dst = WcT + ((size_t)c * DCOMP + o0) * DDIM + d0;
    const int o   = tid >> 2;
    const int dsb = (tid & 3) * 16;
    bf16x8 p0, p1;
#pragma unroll
    for (int k = 0; k < 8; k++) {
      p0[k] = f2bf(tile[dsb + k][o]);
      p1[k] = f2bf(tile[dsb + 8 + k][o]);
    }
    *reinterpret_cast<bf16x8*>(dst + (size_t)o * DDIM + dsb)     = p0;
    *reinterpret_cast<bf16x8*>(dst + (size_t)o * DDIM + dsb + 8) = p1;
  }
}

// =======================================================================
// Bucket builder: 1 block. Reads G (monotonic mask -> k = popcount-1),
// builds ridx = [rows k=3 | k=2 | k=1 | k=0] and cnt[n] = #rows with k>=n.
// Comp n's compacted row list = ridx[0 .. cnt[n]).
// =======================================================================
__global__ __launch_bounds__(1024) void builder_kernel(
    const float* __restrict__ G, unsigned short* __restrict__ ridx,
    int* __restrict__ cnt) {
  __shared__ int hist[4], woff[4];
  const int tid = threadIdx.x;
  if (tid < 4) hist[tid] = 0;
  __syncthreads();
  int kk[4];
#pragma unroll
  for (int p = 0; p < 4; p++) {
    int row = tid + p * 1024;
    float4 g = *reinterpret_cast<const float4*>(G + (size_t)row * 4);
    kk[p] = (int)(g.x + g.y + g.z + g.w) - 1;
    atomicAdd(&hist[kk[p]], 1);
  }
  __syncthreads();
  if (tid == 0) {
    int c3 = hist[3], c2 = hist[2], c1 = hist[1];
    woff[3] = 0; woff[2] = c3; woff[1] = c3 + c2; woff[0] = c3 + c2 + c1;
    cnt[3] = c3; cnt[2] = c3 + c2; cnt[1] = c3 + c2 + c1; cnt[0] = 4096;
  }
  __syncthreads();
#pragma unroll
  for (int p = 0; p < 4; p++) {
    int pos = atomicAdd(&woff[kk[p]], 1);
    ridx[pos] = (unsigned short)(tid + p * 1024);
  }
}

// =======================================================================
// GEMM (compacted rows) + zero-fill, one launch.
// blocks [0,128): zero-fill E rows/comps with mask==0.
// blocks [128,640): compute E[row, comp-block] = x@Wc + bc for compacted
//   rows (mask==1 by construction -> no mask multiply).
// Tile BM=128 x BN=256, BK=64, 8 waves (2M x 4N, 64x64 per wave), 8-phase
// schedule, dbuf LDS 96 KiB, XOR swizzle, counted vmcnt(4)@p4 / vmcnt(6)@p8.
// Stage rotation (iter i; t2=2i+2->buf0, t3=2i+3->buf1):
//   p3: B0.Bh0  p4: B0.Bh1  p5: B0.A   p7: B1.Bh0+Bh1  p8: B1.A
// Reads: p1: A01+bA  p2: bB  p3: A23  p4: regs  (same for buf1 at p5-p8).
// Region audit: every stage targets a region past its last read in the
// cycle; vmcnt(4)@p4 drains prev p7/p8 (buf1), vmcnt(6)@p8 drains p3-p5
// (buf0). Peel iteration needs NO stages (buf1 fully staged prior iter).
// =======================================================================
constexpr int BK = 64;
constexpr int NT = DDIM / BK;    // 32 K-tiles

template<int MB, int NB>
__device__ __forceinline__ void MF(f32x4 (&acc)[4][4], bf16x8 (&a)[2][2], bf16x8 (&b)[2][2]) {
#pragma unroll
  for (int kh = 0; kh < 2; kh++)
#pragma unroll
    for (int i = 0; i < 2; i++)
#pragma unroll
      for (int j = 0; j < 2; j++)
        acc[MB + i][NB + j] = __builtin_amdgcn_mfma_f32_16x16x32_bf16(
            a[i][kh], b[j][kh], acc[MB + i][NB + j], 0, 0, 0);
}

#define PH_SYNC_MFMA(MB, NB, BREG)                           \
  __builtin_amdgcn_s_barrier();                              \
  asm volatile("s_waitcnt lgkmcnt(0)");                      \
  __builtin_amdgcn_s_setprio(1);                             \
  MF<MB, NB>(acc, a, BREG);                                  \
  __builtin_amdgcn_s_setprio(0);

__global__ __launch_bounds__(512, 2) void gemm_kernel(
    const short* __restrict__ xb, const short* __restrict__ wt,
    const float* __restrict__ bc, const float* __restrict__ G,
    const unsigned short* __restrict__ ridx, const int* __restrict__ cnt,
    float* __restrict__ E) {
  __shared__ short Asm[2][128 * 64];   // 2 x 16 KB
  __shared__ short Bsm[2][256 * 64];   // 2 x 32 KB

  const int bid = blockIdx.x;
  const int tid = threadIdx.x;

  if (bid < 128) {
    // ---- zero-fill: rows/comps with mask==0 ----
    for (int rr = 0; rr < 32; rr++) {
      int row = bid * 32 + rr;
      float4 g = *reinterpret_cast<const float4*>(G + (size_t)row * 4);
      int kk = (int)(g.x + g.y + g.z + g.w) - 1;
      for (int n = kk + 1; n < 4; n++) {
        float2* p = reinterpret_cast<float2*>(E + (size_t)row * NOUT + n * DCOMP);
        p[tid] = float2{0.f, 0.f};
      }
    }
    return;
  }

  // ---- compute block ----
  const int cb   = bid - 128;
  const int comp = cb >> 7;
  const int rt   = (cb >> 2) & 31;
  const int ct   = cb & 3;
  const int cntn = cnt[comp];
  if (rt * 128 >= cntn) return;

  const int wave = tid >> 6, lane = tid & 63;
  const int wm = wave >> 2, wn = wave & 3;        // 2M x 4N
  const int fr = lane & 15, fq = lane >> 4, l7 = lane & 7;

  const int colT = comp * DCOMP + ct * 256;       // WcT row base for this tile
  const short* gB = wt + (size_t)colT * DDIM;

  // per-lane staging offsets (linear LDS dest, inverse-swizzled source)
  size_t soffB[2]; const short* gA[2]; int ldst[2];
#pragma unroll
  for (int l = 0; l < 2; l++) {
    int f = l * 512 + tid;
    int r = f >> 3;                  // 0..127
    int s = (f & 7) ^ (r & 7);
    soffB[l] = (size_t)r * DDIM + s * 8;
    int g = rt * 128 + r;
    g = (g < cntn) ? g : (cntn - 1);               // tail clamp (pad = dup row)
    gA[l] = xb + (size_t)ridx[g] * DDIM + s * 8;   // gathered row base
    ldst[l] = (l * 512 + wave * 64) * 8;           // wave-uniform LDS base
  }

  auto STAGE_A = [&](int buf, int t) {
#pragma unroll
    for (int l = 0; l < 2; l++)
      GLOAD_LDS16(gA[l] + t * 64, &Asm[buf][0] + ldst[l]);
  };
  auto STAGE_B = [&](int buf, int t, int h) {
#pragma unroll
    for (int l = 0; l < 2; l++)
      GLOAD_LDS16(gB + (size_t)(h * 128) * DDIM + t * 64 + soffB[l],
                  &Bsm[buf][h * 8192] + ldst[l]);
  };
  auto LDA = [&](int buf, int MB, bf16x8 (&a)[2][2]) {
#pragma unroll
    for (int i = 0; i < 2; i++) {
      int rh = wm * 64 + (MB + i) * 16 + fr;
#pragma unroll
      for (int kh = 0; kh < 2; kh++) {
        int sl = ((kh * 4 + fq) ^ l7) * 8;
        a[i][kh] = *reinterpret_cast<const bf16x8*>(&Asm[buf][rh * 64 + sl]);
      }
    }
  };
  auto LDB = [&](int buf, int NB, bf16x8 (&b)[2][2]) {
#pragma unroll
    for (int j = 0; j < 2; j++) {
      int ch = wn * 64 + (NB + j) * 16 + fr;       // 0..255 spans both halves
#pragma unroll
      for (int kh = 0; kh < 2; kh++) {
        int sl = ((kh * 4 + fq) ^ l7) * 8;
        b[j][kh] = *reinterpret_cast<const bf16x8*>(&Bsm[buf][ch * 64 + sl]);
      }
    }
  };

  f32x4 acc[4][4];
#pragma unroll
  for (int m = 0; m < 4; m++)
#pragma unroll
    for (int n = 0; n < 4; n++) acc[m][n] = f32x4{0.f, 0.f, 0.f, 0.f};
  bf16x8 a[2][2], bA[2][2], bB[2][2];

  // ---- prologue: tile0 -> buf0, tile1 -> buf1; drain tile0, keep tile1 ----
  STAGE_B(0, 0, 0); STAGE_B(0, 0, 1); STAGE_A(0, 0);
  STAGE_B(1, 1, 0); STAGE_B(1, 1, 1); STAGE_A(1, 1);
  asm volatile("s_waitcnt vmcnt(6)" ::: "memory");
  __builtin_amdgcn_s_barrier();

  // ---- main loop (iters 0..NT/2-2) ----
  for (int i = 0; i < NT / 2 - 1; i++) {
    const int t2 = 2 * i + 2, t3 = 2 * i + 3;

    // p1: (mh0,nh0) buf0
    LDA(0, 0, a); LDB(0, 0, bA);
    PH_SYNC_MFMA(0, 0, bA);
    __builtin_amdgcn_s_barrier();
    // p2: (mh0,nh1)
    LDB(0, 2, bB);
    PH_SYNC_MFMA(0, 2, bB);
    __builtin_amdgcn_s_barrier();
    // p3: (mh1,nh1)  [B-buf0 free after p2 -> stage]
    LDA(0, 2, a);
    STAGE_B(0, t2, 0);
    PH_SYNC_MFMA(2, 2, bB);
    __builtin_amdgcn_s_barrier();
    // p4: (mh1,nh0) regs only + counted vmcnt (drains prev p7/p8 = buf1)
    STAGE_B(0, t2, 1);
    PH_SYNC_MFMA(2, 0, bA);
    asm volatile("s_waitcnt vmcnt(4)" ::: "memory");
    __builtin_amdgcn_s_barrier();
    // p5: (mh0,nh0) buf1  [A-buf0 free after p3 -> stage]
    LDA(1, 0, a); LDB(1, 0, bA);
    STAGE_A(0, t2);
    PH_SYNC_MFMA(0, 0, bA);
    __builtin_amdgcn_s_barrier();
    // p6: (mh0,nh1)
    LDB(1, 2, bB);
    PH_SYNC_MFMA(0, 2, bB);
    __builtin_amdgcn_s_barrier();
    // p7: (mh1,nh1)  [B-buf1 free after p6 -> stage both halves]
    LDA(1, 2, a);
    STAGE_B(1, t3, 0); STAGE_B(1, t3, 1);
    PH_SYNC_MFMA(2, 2, bB);
    __builtin_amdgcn_s_barrier();
    // p8: (mh1,nh0) regs only + counted vmcnt (drains p3/p4/p5 = buf0)
    STAGE_A(1, t3);
    PH_SYNC_MFMA(2, 0, bA);
    asm volatile("s_waitcnt vmcnt(6)" ::: "memory");
    __builtin_amdgcn_s_barrier();
  }

  // ---- peeled last iteration (tiles NT-2, NT-1): no stages needed ----
  {
    LDA(0, 0, a); LDB(0, 0, bA);
    PH_SYNC_MFMA(0, 0, bA);
    __builtin_amdgcn_s_barrier();
    LDB(0, 2, bB);
    PH_SYNC_MFMA(0, 2, bB);
    __builtin_amdgcn_s_barrier();
    LDA(0, 2, a);
    PH_SYNC_MFMA(2, 2, bB);
    __builtin_amdgcn_s_barrier();
    PH_SYNC_MFMA(2, 0, bA);
    asm volatile("s_waitcnt vmcnt(0)" ::: "memory");   // buf1 (tile NT-1) lands
    __builtin_amdgcn_s_barrier();
    LDA(1, 0, a); LDB(1, 0, bA);
    PH_SYNC_MFMA(0, 0, bA);
    __builtin_amdgcn_s_barrier();
    LDB(1, 2, bB);
    PH_SYNC_MFMA(0, 2, bB);
    __builtin_amdgcn_s_barrier();
    LDA(1, 2, a);
    PH_SYNC_MFMA(2, 2, bB);
    __builtin_amdgcn_s_barrier();
    PH_SYNC_MFMA(2, 0, bA);
  }

  // ---- epilogue: + bias, gathered-row store (mask==1 rows only) ----
  const int rit = cntn - rt * 128;   // valid rows in this tile (1..128)
  float bias[4];
#pragma unroll
  for (int n = 0; n < 4; n++)
    bias[n] = bc[colT + wn * 64 + n * 16 + fr];
#pragma unroll
  for (int m = 0; m < 4; m++) {
#pragma unroll
    for (int j = 0; j < 4; j++) {
      int rl = wm * 64 + m * 16 + fq * 4 + j;
      if (rl < rit) {
        int row = ridx[rt * 128 + rl];
        float* Erow = E + (size_t)row * NOUT + colT + wn * 64;
#pragma unroll
        for (int n = 0; n < 4; n++)
          Erow[n * 16 + fr] = acc[m][n][j] + bias[n];
      }
    }
  }
}

extern "C" void kernel_launch(void* const* d_in, const int* in_sizes, int n_in,
                              void* d_out, int out_size, void* d_ws, size_t ws_size,
                              hipStream_t stream) {
  const float* x     = (const float*)d_in[0];
  const float* noise = (const float*)d_in[1];
  const float* Wc    = (const float*)d_in[2];
  const float* bc    = (const float*)d_in[3];
  const float* Wg    = (const float*)d_in[4];
  const float* bg    = (const float*)d_in[5];
  const float* Wn    = (const float*)d_in[6];
  const float* bn    = (const float*)d_in[7];

  float* E = (float*)d_out;                          // [4096, 4096]
  float* G = (float*)d_out + (size_t)BROWS * NOUT;   // [4096, 4]

  char* ws = (char*)d_ws;
  short*          xbuf = (short*)ws;                              // 16 MB
  short*          WcT  = (short*)(ws + (size_t)16 * 1024 * 1024); // 16 MB
  unsigned short* ridx = (unsigned short*)(ws + (size_t)32 * 1024 * 1024); // 8 KB
  int*            cnt  = (int*)(ws + (size_t)32 * 1024 * 1024 + 8192);     // 16 B

  prep_kernel<<<3072, 256, 0, stream>>>(x, noise, Wg, bg, Wn, bn, Wc, G, xbuf, WcT);
  builder_kernel<<<1, 1024, 0, stream>>>(G, ridx, cnt);
  gemm_kernel<<<640, 512, 0, stream>>>(xbuf, WcT, bc, G, ridx, cnt, E);
}

// Round 8
// 100.355 us; speedup vs baseline: 1.0540x; 1.0540x over previous
//
#include <hip/hip_runtime.h>
#include <hip/hip_bf16.h>
#include <math.h>

constexpr int BROWS = 4096;   // batch (M)
constexpr int DDIM  = 2048;   // input features (K)
constexpr int NCOMP = 4;
constexpr int DCOMP = 1024;
constexpr int NOUT  = NCOMP * DCOMP;  // 4096 output cols

typedef __attribute__((ext_vector_type(8))) short bf16x8;
typedef __attribute__((ext_vector_type(4))) float f32x4;
typedef __attribute__((ext_vector_type(4))) short s16x4;

__device__ __forceinline__ short f2bf(float f) {
  union { float f; unsigned u; } v; v.f = f;
  unsigned r = v.u + 0x7FFFu + ((v.u >> 16) & 1u);  // round-to-nearest-even
  return (short)(r >> 16);
}

#define GLOAD_LDS16(gptr, lptr) __builtin_amdgcn_global_load_lds( \
    (const __attribute__((address_space(1))) void*)(gptr),        \
    (__attribute__((address_space(3))) void*)(lptr), 16, 0, 0)

// =======================================================================
// Prep (r5-proven): blocks [0,1024) gating (1 row/wave) + x f32->bf16;
// [1024,3072) Wc transpose+convert to B^T bf16.
// =======================================================================
__global__ __launch_bounds__(256) void prep_kernel(
    const float* __restrict__ x, const float* __restrict__ noise,
    const float* __restrict__ Wg, const float* __restrict__ bg,
    const float* __restrict__ Wn, const float* __restrict__ bn,
    const float* __restrict__ Wc,
    float* __restrict__ Gout, short* __restrict__ xb, short* __restrict__ WcT) {
  __shared__ float tile[64][65];
  const int bid = blockIdx.x;
  const int tid = threadIdx.x;

  if (bid < 1024) {
    const int lane = tid & 63;
    const int row  = bid * 4 + (tid >> 6);
    const float* xr = x + (size_t)row * DDIM;
    short* xbr = xb + (size_t)row * DDIM;

    float ag[4] = {0.f, 0.f, 0.f, 0.f};
    float an[4] = {0.f, 0.f, 0.f, 0.f};
#pragma unroll
    for (int i = 0; i < 8; i++) {
      int d = i * 256 + lane * 4;
      float4 v = *reinterpret_cast<const float4*>(xr + d);
      s16x4 s; s.x = f2bf(v.x); s.y = f2bf(v.y); s.z = f2bf(v.z); s.w = f2bf(v.w);
      *reinterpret_cast<s16x4*>(xbr + d) = s;
      float xv[4] = {v.x, v.y, v.z, v.w};
#pragma unroll
      for (int j = 0; j < 4; j++) {
        float4 wg = *reinterpret_cast<const float4*>(Wg + 4 * (d + j));
        float4 wn = *reinterpret_cast<const float4*>(Wn + 4 * (d + j));
        ag[0] += xv[j] * wg.x; ag[1] += xv[j] * wg.y;
        ag[2] += xv[j] * wg.z; ag[3] += xv[j] * wg.w;
        an[0] += xv[j] * wn.x; an[1] += xv[j] * wn.y;
        an[2] += xv[j] * wn.z; an[3] += xv[j] * wn.w;
      }
    }
#pragma unroll
    for (int off = 32; off > 0; off >>= 1) {
#pragma unroll
      for (int c = 0; c < 4; c++) {
        ag[c] += __shfl_xor(ag[c], off);
        an[c] += __shfl_xor(an[c], off);
      }
    }
    if (lane == 0) {
      float H[4];
#pragma unroll
      for (int c = 0; c < 4; c++) {
        float v  = an[c] + bn[c];
        float sp = (v > 20.f) ? v : log1pf(expf(v));
        H[c] = (ag[c] + bg[c]) + noise[(size_t)row * NCOMP + c] * sp;
      }
      int k = 0; float best = H[0];
#pragma unroll
      for (int c = 1; c < 4; c++) { if (H[c] > best) { best = H[c]; k = c; } }
#pragma unroll
      for (int c = 0; c < 4; c++)
        Gout[(size_t)row * NCOMP + c] = (c <= k) ? 1.0f : 0.0f;
    }
  } else {
    const int tb  = bid - 1024;
    const int o_t = tb & 15, d_t = (tb >> 4) & 31, c = tb >> 9;
    const int d0 = d_t * 64, o0 = o_t * 64;
    const int col = tid & 63, rb = tid >> 6;

    const float* src = Wc + ((size_t)c * DDIM + d0) * DCOMP + o0;
#pragma unroll
    for (int i = 0; i < 16; i++) {
      int r = rb + i * 4;
      tile[r][col] = src[(size_t)r * DCOMP + col];
    }
    __syncthreads();
    short* dst = WcT + ((size_t)c * DCOMP + o0) * DDIM + d0;
    const int o   = tid >> 2;
    const int dsb = (tid & 3) * 16;
    bf16x8 p0, p1;
#pragma unroll
    for (int k = 0; k < 8; k++) {
      p0[k] = f2bf(tile[dsb + k][o]);
      p1[k] = f2bf(tile[dsb + 8 + k][o]);
    }
    *reinterpret_cast<bf16x8*>(dst + (size_t)o * DDIM + dsb)     = p0;
    *reinterpret_cast<bf16x8*>(dst + (size_t)o * DDIM + dsb + 8) = p1;
  }
}

// =======================================================================
// Main GEMM: E = mask * (xb @ WcT^T + bc)
// 256x256, BK=64, 8 waves (2Mx4N, 128x64/wave), 8-phase K-loop with
// REGISTER-FRAGMENT PIPELINING: phase p reads frags for phase p+1 while
// MFMA consumes frags read at p-1 (ds latency hidden under MFMA).
// Uniform ledger (audited): 1 half-stage/phase, every region staged
// EXACTLY 6 phases before its read; uniform vmcnt(10) at every phase top
// (leaves 5 stages in flight, never 0); every overwrite >= 2 phases after
// the region's last read-issue; 1 barrier/phase.
//   MFMA quadrants: p1(0,0)aP.bA p2(4,0)aQ.bA p3(4,2)aQ.bB p4(0,2)aP.bB
//                   p5(4,0)aQ.bA p6(0,0)aP.bA p7(0,2)aP.bB p8(4,2)aQ.bB
//   Reads (for next use): p1 aQ<-b0.Ah1, p2 bB<-b0.Bh1, p3 bA<-b1.Bh0,
//     p4 aQ<-b1.Ah1, p5 aP<-b1.Ah0, p6 bB<-b1.Bh1, p7 bA<-b0.Bh0[T2],
//     p8 aP<-b0.Ah0[T2]
//   Stages: p1 b0.Bh0<-T2, p2 b0.Ah0<-T2, p3 b0.Ah1<-T2, p4 b0.Bh1<-T2,
//           p5 b1.Bh0<-T3, p6 b1.Ah1<-T3, p7 b1.Ah0<-T3, p8 b1.Bh1<-T3
// =======================================================================
constexpr int BM = 256, BN = 256, BK = 64;
constexpr int NT = DDIM / BK;    // 32 K-tiles
constexpr int HS = 128 * 64;     // shorts per half-tile (16 KB)

template<int MB, int NB>
__device__ __forceinline__ void MF(f32x4 (&acc)[8][4], bf16x8 (&a)[4][2], bf16x8 (&b)[2][2]) {
#pragma unroll
  for (int kh = 0; kh < 2; kh++)
#pragma unroll
    for (int ml = 0; ml < 4; ml++)
#pragma unroll
      for (int nl = 0; nl < 2; nl++)
        acc[MB + ml][NB + nl] = __builtin_amdgcn_mfma_f32_16x16x32_bf16(
            a[ml][kh], b[nl][kh], acc[MB + ml][NB + nl], 0, 0, 0);
}

// phase top: per-wave vmcnt drain, then barrier (=> all waves drained =>
// regions staged 6 phases ago are globally resident for this phase's reads)
#define PH_TOP(N)                                            \
  asm volatile("s_waitcnt vmcnt(" #N ")" ::: "memory");      \
  __builtin_amdgcn_s_barrier();

// MFMA cluster: pin read/stage issue before it, boost priority
#define PH_MFMA(MB, NB, AREG, BREG)                          \
  __builtin_amdgcn_sched_barrier(0);                         \
  __builtin_amdgcn_s_setprio(1);                             \
  MF<MB, NB>(acc, AREG, BREG);                               \
  __builtin_amdgcn_s_setprio(0);

__global__ __launch_bounds__(512, 2) void gemm_kernel(
    const short* __restrict__ xb, const short* __restrict__ wt,
    const float* __restrict__ bc, const float* __restrict__ G,
    float* __restrict__ E) {
  __shared__ short Asm[2][2][HS];   // [buf][half][128r * 8slot * 8bf16]
  __shared__ short Bsm[2][2][HS];

  const int tid  = threadIdx.x;
  const int wave = tid >> 6, lane = tid & 63;
  const int wm = wave >> 2, wn = wave & 3;
  const int fr = lane & 15, fq = lane >> 4, l7 = lane & 7;

  // XCD swizzle: 8 XCDs x (4x8 chunk, column-major walk)
  const int xcd = blockIdx.x & 7, j = blockIdx.x >> 3;
  const int trow0 = (((xcd >> 1) << 2) + (j & 3)) * BM;
  const int tcol0 = (((xcd & 1) << 3) + (j >> 2)) * BN;

  const short* baseA[2] = { xb + (size_t)(trow0      ) * DDIM,
                            xb + (size_t)(trow0 + 128) * DDIM };
  const short* baseB[2] = { wt + (size_t)(tcol0      ) * DDIM,
                            wt + (size_t)(tcol0 + 128) * DDIM };

  // per-lane staging source offsets (linear LDS dest, inverse-swizzled src)
  size_t soff[2]; int ldst[2];
#pragma unroll
  for (int l = 0; l < 2; l++) {
    int f = l * 512 + tid;
    int r = f >> 3;
    int s = (f & 7) ^ (r & 7);
    soff[l] = (size_t)r * DDIM + s * 8;
    ldst[l] = (l * 512 + wave * 64) * 8;
  }

  auto STAGE = [&](const short* gb, int t, short* ldsh) {
#pragma unroll
    for (int l = 0; l < 2; l++)
      GLOAD_LDS16(gb + t * 64 + soff[l], ldsh + ldst[l]);
  };
  auto LDA = [&](const short* Ah, bf16x8 (&a)[4][2]) {
#pragma unroll
    for (int ml = 0; ml < 4; ml++) {
      int rh = wm * 64 + ml * 16 + fr;
#pragma unroll
      for (int kh = 0; kh < 2; kh++) {
        int sl = ((kh * 4 + fq) ^ l7) * 8;
        a[ml][kh] = *reinterpret_cast<const bf16x8*>(Ah + rh * 64 + sl);
      }
    }
  };
  auto LDB = [&](const short* Bh, bf16x8 (&b)[2][2]) {
#pragma unroll
    for (int nl = 0; nl < 2; nl++) {
      int ch = wn * 32 + nl * 16 + fr;
#pragma unroll
      for (int kh = 0; kh < 2; kh++) {
        int sl = ((kh * 4 + fq) ^ l7) * 8;
        b[nl][kh] = *reinterpret_cast<const bf16x8*>(Bh + ch * 64 + sl);
      }
    }
  };

  f32x4 acc[8][4];
#pragma unroll
  for (int m = 0; m < 8; m++)
#pragma unroll
    for (int n = 0; n < 4; n++) acc[m][n] = f32x4{0.f, 0.f, 0.f, 0.f};
  bf16x8 aP[4][2], aQ[4][2], bA[2][2], bB[2][2];

  // ---- prologue: stage all 8 halves (b0<-T0, b1<-T1) in ledger order;
  // drain the first two (b0.Ah0, b0.Bh0); barrier; pre-read aP,bA. ----
  STAGE(baseA[0], 0, &Asm[0][0][0]);   // [1] b0.Ah0
  STAGE(baseB[0], 0, &Bsm[0][0][0]);   // [2] b0.Bh0
  STAGE(baseA[1], 0, &Asm[0][1][0]);   // [3] b0.Ah1
  STAGE(baseB[1], 0, &Bsm[0][1][0]);   // [4] b0.Bh1
  STAGE(baseB[0], 1, &Bsm[1][0][0]);   // [5] b1.Bh0
  STAGE(baseA[1], 1, &Asm[1][1][0]);   // [6] b1.Ah1
  STAGE(baseA[0], 1, &Asm[1][0][0]);   // [7] b1.Ah0
  STAGE(baseB[1], 1, &Bsm[1][1][0]);   // [8] b1.Bh1
  asm volatile("s_waitcnt vmcnt(12)" ::: "memory");   // [1],[2] landed
  __builtin_amdgcn_s_barrier();
  LDA(&Asm[0][0][0], aP);              // b0.Ah0 -> aP (for p1,p4)
  LDB(&Bsm[0][0][0], bA);              // b0.Bh0 -> bA (for p1,p2)

  // ---- main loop: iter i consumes tiles 2i (buf0) and 2i+1 (buf1);
  // stages T2=2i+2 (p1-p4) and T3=2i+3 (p5-p8). 15 full iters + peel. ----
  for (int i = 0; i < NT / 2 - 1; i++) {
    const int t2 = 2 * i + 2, t3 = 2 * i + 3;

    // p1
    PH_TOP(10);                                    // drains b0.Ah1 stage
    LDA(&Asm[0][1][0], aQ);                        // for p2,p3
    STAGE(baseB[0], t2, &Bsm[0][0][0]);
    PH_MFMA(0, 0, aP, bA);
    // p2
    PH_TOP(10);                                    // drains b0.Bh1
    LDB(&Bsm[0][1][0], bB);                        // for p3,p4
    STAGE(baseA[0], t2, &Asm[0][0][0]);
    PH_MFMA(4, 0, aQ, bA);
    // p3
    PH_TOP(10);                                    // drains b1.Bh0
    LDB(&Bsm[1][0][0], bA);                        // for p5,p6
    STAGE(baseA[1], t2, &Asm[0][1][0]);
    PH_MFMA(4, 2, aQ, bB);
    // p4
    PH_TOP(10);                                    // drains b1.Ah1
    LDA(&Asm[1][1][0], aQ);                        // for p5,p8
    STAGE(baseB[1], t2, &Bsm[0][1][0]);
    PH_MFMA(0, 2, aP, bB);
    // p5
    PH_TOP(10);                                    // drains b1.Ah0
    LDA(&Asm[1][0][0], aP);                        // for p6,p7
    STAGE(baseB[0], t3, &Bsm[1][0][0]);
    PH_MFMA(4, 0, aQ, bA);
    // p6
    PH_TOP(10);                                    // drains b1.Bh1
    LDB(&Bsm[1][1][0], bB);                        // for p7,p8
    STAGE(baseA[1], t3, &Asm[1][1][0]);
    PH_MFMA(0, 0, aP, bA);
    // p7
    PH_TOP(10);                                    // drains b0.Bh0[T2]
    LDB(&Bsm[0][0][0], bA);                        // for next p1,p2
    STAGE(baseA[0], t3, &Asm[1][0][0]);
    PH_MFMA(0, 2, aP, bB);
    // p8
    PH_TOP(10);                                    // drains b0.Ah0[T2]
    LDA(&Asm[0][0][0], aP);                        // for next p1,p4
    STAGE(baseB[1], t3, &Bsm[1][1][0]);
    PH_MFMA(4, 2, aQ, bB);
  }

  // ---- peel (tiles NT-2 buf0, NT-1 buf1): no stages; skip p7/p8 reads ----
  {
    PH_TOP(10);
    LDA(&Asm[0][1][0], aQ);
    PH_MFMA(0, 0, aP, bA);
    PH_TOP(8);
    LDB(&Bsm[0][1][0], bB);
    PH_MFMA(4, 0, aQ, bA);
    PH_TOP(6);
    LDB(&Bsm[1][0][0], bA);
    PH_MFMA(4, 2, aQ, bB);
    PH_TOP(4);
    LDA(&Asm[1][1][0], aQ);
    PH_MFMA(0, 2, aP, bB);
    PH_TOP(2);
    LDA(&Asm[1][0][0], aP);
    PH_MFMA(4, 0, aQ, bA);
    PH_TOP(0);
    LDB(&Bsm[1][1][0], bB);
    PH_MFMA(0, 0, aP, bA);
    __builtin_amdgcn_s_barrier();
    PH_MFMA(0, 2, aP, bB);
    __builtin_amdgcn_s_barrier();
    PH_MFMA(4, 2, aQ, bB);
  }

  // ---- epilogue: + bias, * mask, store f32 ----
  const int comp = tcol0 >> 10;
  const float* __restrict__ bcn = bc + (size_t)comp * DCOMP + (tcol0 & (DCOMP - 1));
  float bias[4];
#pragma unroll
  for (int n = 0; n < 4; n++)
    bias[n] = bcn[((n >> 1) * 128) + wn * 32 + (n & 1) * 16 + fr];
#pragma unroll
  for (int m = 0; m < 8; m++) {
    int growb = trow0 + ((m >> 2) * 128) + wm * 64 + (m & 3) * 16 + fq * 4;
#pragma unroll
    for (int j = 0; j < 4; j++) {
      int r = growb + j;
      float mval = G[(size_t)r * NCOMP + comp];
      float* Erow = E + (size_t)r * NOUT + tcol0;
#pragma unroll
      for (int n = 0; n < 4; n++) {
        int coll = ((n >> 1) * 128) + wn * 32 + (n & 1) * 16 + fr;
        Erow[coll] = mval * (acc[m][n][j] + bias[n]);
      }
    }
  }
}

extern "C" void kernel_launch(void* const* d_in, const int* in_sizes, int n_in,
                              void* d_out, int out_size, void* d_ws, size_t ws_size,
                              hipStream_t stream) {
  const float* x     = (const float*)d_in[0];
  const float* noise = (const float*)d_in[1];
  const float* Wc    = (const float*)d_in[2];
  const float* bc    = (const float*)d_in[3];
  const float* Wg    = (const float*)d_in[4];
  const float* bg    = (const float*)d_in[5];
  const float* Wn    = (const float*)d_in[6];
  const float* bn    = (const float*)d_in[7];

  float* E = (float*)d_out;                          // [4096, 4096]
  float* G = (float*)d_out + (size_t)BROWS * NOUT;   // [4096, 4]

  short* xb  = (short*)d_ws;                         // 16 MB bf16
  short* WcT = xb + (size_t)BROWS * DDIM;            // 16 MB bf16

  prep_kernel<<<3072, 256, 0, stream>>>(x, noise, Wg, bg, Wn, bn, Wc, G, xb, WcT);
  gemm_kernel<<<256, 512, 0, stream>>>(xb, WcT, bc, G, E);
}

// Round 9
// 91.626 us; speedup vs baseline: 1.1544x; 1.0953x over previous
//
#include <hip/hip_runtime.h>
#include <hip/hip_bf16.h>
#include <math.h>

constexpr int BROWS = 4096;   // batch (M)
constexpr int DDIM  = 2048;   // input features (K)
constexpr int NCOMP = 4;
constexpr int DCOMP = 1024;
constexpr int NOUT  = NCOMP * DCOMP;  // 4096 output cols

typedef __attribute__((ext_vector_type(8))) short bf16x8;
typedef __attribute__((ext_vector_type(4))) float f32x4;
typedef __attribute__((ext_vector_type(4))) short s16x4;

__device__ __forceinline__ short f2bf(float f) {
  union { float f; unsigned u; } v; v.f = f;
  unsigned r = v.u + 0x7FFFu + ((v.u >> 16) & 1u);  // round-to-nearest-even
  return (short)(r >> 16);
}

#define GLOAD_LDS16(gptr, lptr) __builtin_amdgcn_global_load_lds( \
    (const __attribute__((address_space(1))) void*)(gptr),        \
    (__attribute__((address_space(3))) void*)(lptr), 16, 0, 0)

// =======================================================================
// Prep (r5-proven, ~19.5us): blocks [0,1024) gating (1 row/wave) +
// x f32->bf16; [1024,3072) Wc transpose+convert to B^T bf16.
// =======================================================================
__global__ __launch_bounds__(256) void prep_kernel(
    const float* __restrict__ x, const float* __restrict__ noise,
    const float* __restrict__ Wg, const float* __restrict__ bg,
    const float* __restrict__ Wn, const float* __restrict__ bn,
    const float* __restrict__ Wc,
    float* __restrict__ Gout, short* __restrict__ xb, short* __restrict__ WcT) {
  __shared__ float tile[64][65];
  const int bid = blockIdx.x;
  const int tid = threadIdx.x;

  if (bid < 1024) {
    const int lane = tid & 63;
    const int row  = bid * 4 + (tid >> 6);
    const float* xr = x + (size_t)row * DDIM;
    short* xbr = xb + (size_t)row * DDIM;

    float ag[4] = {0.f, 0.f, 0.f, 0.f};
    float an[4] = {0.f, 0.f, 0.f, 0.f};
#pragma unroll
    for (int i = 0; i < 8; i++) {
      int d = i * 256 + lane * 4;
      float4 v = *reinterpret_cast<const float4*>(xr + d);
      s16x4 s; s.x = f2bf(v.x); s.y = f2bf(v.y); s.z = f2bf(v.z); s.w = f2bf(v.w);
      *reinterpret_cast<s16x4*>(xbr + d) = s;
      float xv[4] = {v.x, v.y, v.z, v.w};
#pragma unroll
      for (int j = 0; j < 4; j++) {
        float4 wg = *reinterpret_cast<const float4*>(Wg + 4 * (d + j));
        float4 wn = *reinterpret_cast<const float4*>(Wn + 4 * (d + j));
        ag[0] += xv[j] * wg.x; ag[1] += xv[j] * wg.y;
        ag[2] += xv[j] * wg.z; ag[3] += xv[j] * wg.w;
        an[0] += xv[j] * wn.x; an[1] += xv[j] * wn.y;
        an[2] += xv[j] * wn.z; an[3] += xv[j] * wn.w;
      }
    }
#pragma unroll
    for (int off = 32; off > 0; off >>= 1) {
#pragma unroll
      for (int c = 0; c < 4; c++) {
        ag[c] += __shfl_xor(ag[c], off);
        an[c] += __shfl_xor(an[c], off);
      }
    }
    if (lane == 0) {
      float H[4];
#pragma unroll
      for (int c = 0; c < 4; c++) {
        float v  = an[c] + bn[c];
        float sp = (v > 20.f) ? v : log1pf(expf(v));
        H[c] = (ag[c] + bg[c]) + noise[(size_t)row * NCOMP + c] * sp;
      }
      int k = 0; float best = H[0];
#pragma unroll
      for (int c = 1; c < 4; c++) { if (H[c] > best) { best = H[c]; k = c; } }
#pragma unroll
      for (int c = 0; c < 4; c++)
        Gout[(size_t)row * NCOMP + c] = (c <= k) ? 1.0f : 0.0f;
    }
  } else {
    const int tb  = bid - 1024;
    const int o_t = tb & 15, d_t = (tb >> 4) & 31, c = tb >> 9;
    const int d0 = d_t * 64, o0 = o_t * 64;
    const int col = tid & 63, rb = tid >> 6;

    const float* src = Wc + ((size_t)c * DDIM + d0) * DCOMP + o0;
#pragma unroll
    for (int i = 0; i < 16; i++) {
      int r = rb + i * 4;
      tile[r][col] = src[(size_t)r * DCOMP + col];
    }
    __syncthreads();
    short* dst = WcT + ((size_t)c * DCOMP + o0) * DDIM + d0;
    const int o   = tid >> 2;
    const int dsb = (tid & 3) * 16;
    bf16x8 p0, p1;
#pragma unroll
    for (int k = 0; k < 8; k++) {
      p0[k] = f2bf(tile[dsb + k][o]);
      p1[k] = f2bf(tile[dsb + 8 + k][o]);
    }
    *reinterpret_cast<bf16x8*>(dst + (size_t)o * DDIM + dsb)     = p0;
    *reinterpret_cast<bf16x8*>(dst + (size_t)o * DDIM + dsb + 8) = p1;
  }
}

// =======================================================================
// Main GEMM (r6-proven, 72.1us / 954 TF): 256x256 tile, BK=64, 8 waves
// (2Mx4N), 8-phase schedule, dbuf half-tile LDS (128 KiB), XOR swizzle,
// b[nh0] register-held p1->p4 (bA) + bB for nh1 (24 b128/wave/K-tile),
// uniform 1 half-stage/phase rotation, counted vmcnt(6) at p4/p8 only,
// bare lgkmcnt(0) per phase, setprio around MFMA, XCD 4x8 chunked swizzle.
// Stage rotation (iter i; t1=2i+1, t2=2i+2, t3=2i+3):
//   p1: B1.Ah1<-t1   p2: B0.Ah0<-t2   p3: B0.Bh0<-t2   p4: B0.Bh1<-t2
//   p5: B0.Ah1<-t2   p6: B1.Ah0<-t3   p7: B1.Bh0<-t3   p8: B1.Bh1<-t3
// Reads: p1: B0.Ah0+B0.Bh0(->bA)  p2: B0.Bh1(->bB)  p3: B0.Ah1  p4: regs
//        p5: B1.Ah0+B1.Bh0(->bA)  p6: B1.Bh1(->bB)  p7: B1.Ah1  p8: regs
// =======================================================================
constexpr int BM = 256, BN = 256, BK = 64;
constexpr int NT = DDIM / BK;    // 32 K-tiles
constexpr int HS = 128 * 64;     // shorts per half-tile (16 KB)

template<int MB, int NB>
__device__ __forceinline__ void MF(f32x4 (&acc)[8][4], bf16x8 (&a)[4][2], bf16x8 (&b)[2][2]) {
#pragma unroll
  for (int kh = 0; kh < 2; kh++)
#pragma unroll
    for (int ml = 0; ml < 4; ml++)
#pragma unroll
      for (int nl = 0; nl < 2; nl++)
        acc[MB + ml][NB + nl] = __builtin_amdgcn_mfma_f32_16x16x32_bf16(
            a[ml][kh], b[nl][kh], acc[MB + ml][NB + nl], 0, 0, 0);
}

#define PH_SYNC_MFMA(MB, NB, BREG)                           \
  __builtin_amdgcn_s_barrier();                              \
  asm volatile("s_waitcnt lgkmcnt(0)");                      \
  __builtin_amdgcn_s_setprio(1);                             \
  MF<MB, NB>(acc, a, BREG);                                  \
  __builtin_amdgcn_s_setprio(0);

__global__ __launch_bounds__(512, 2) void gemm_kernel(
    const short* __restrict__ xb, const short* __restrict__ wt,
    const float* __restrict__ bc, const float* __restrict__ G,
    float* __restrict__ E) {
  __shared__ short Asm[2][2][HS];   // [buf][row-half][128r * 8slot * 8bf16]
  __shared__ short Bsm[2][2][HS];   // [buf][col-half][...]

  const int tid  = threadIdx.x;
  const int wave = tid >> 6, lane = tid & 63;
  const int wm = wave >> 2, wn = wave & 3;
  const int fr = lane & 15, fq = lane >> 4, l7 = lane & 7;

  // XCD swizzle: 16x16 tile grid, 8 XCDs, each owns a 4x8 chunk (col-major)
  const int xcd = blockIdx.x & 7, j = blockIdx.x >> 3;
  const int trow0 = (((xcd >> 1) << 2) + (j & 3)) * BM;
  const int tcol0 = (((xcd & 1) << 3) + (j >> 2)) * BN;

  const short* baseA[2] = { xb + (size_t)(trow0      ) * DDIM,
                            xb + (size_t)(trow0 + 128) * DDIM };
  const short* baseB[2] = { wt + (size_t)(tcol0      ) * DDIM,
                            wt + (size_t)(tcol0 + 128) * DDIM };

  // per-lane staging offsets (linear LDS dest, inverse-swizzled source)
  size_t soff[2]; int ldst[2];
#pragma unroll
  for (int l = 0; l < 2; l++) {
    int f = l * 512 + tid;
    int r = f >> 3;
    int s = (f & 7) ^ (r & 7);
    soff[l] = (size_t)r * DDIM + s * 8;
    ldst[l] = (l * 512 + wave * 64) * 8;   // wave-uniform LDS base (shorts)
  }

  auto STAGE = [&](const short* gb, int t, short* ldsh) {
#pragma unroll
    for (int l = 0; l < 2; l++)
      GLOAD_LDS16(gb + t * 64 + soff[l], ldsh + ldst[l]);
  };
  auto LDA = [&](const short* Ah, bf16x8 (&a)[4][2]) {
#pragma unroll
    for (int ml = 0; ml < 4; ml++) {
      int rh = wm * 64 + ml * 16 + fr;
#pragma unroll
      for (int kh = 0; kh < 2; kh++) {
        int sl = ((kh * 4 + fq) ^ l7) * 8;
        a[ml][kh] = *reinterpret_cast<const bf16x8*>(Ah + rh * 64 + sl);
      }
    }
  };
  auto LDB = [&](const short* Bh, bf16x8 (&b)[2][2]) {
#pragma unroll
    for (int nl = 0; nl < 2; nl++) {
      int ch = wn * 32 + nl * 16 + fr;
#pragma unroll
      for (int kh = 0; kh < 2; kh++) {
        int sl = ((kh * 4 + fq) ^ l7) * 8;
        b[nl][kh] = *reinterpret_cast<const bf16x8*>(Bh + ch * 64 + sl);
      }
    }
  };

  f32x4 acc[8][4];
#pragma unroll
  for (int m = 0; m < 8; m++)
#pragma unroll
    for (int n = 0; n < 4; n++) acc[m][n] = f32x4{0.f, 0.f, 0.f, 0.f};
  bf16x8 a[4][2], bA[2][2], bB[2][2];

  // ---- prologue: tile0 (4 halves) + tile1 {Ah0,Bh0,Bh1}; vmcnt(6) keeps
  // the tile1 trio in flight; tile1.Ah1 staged at p1 of iter 0. ----
  STAGE(baseA[0], 0, &Asm[0][0][0]);
  STAGE(baseB[0], 0, &Bsm[0][0][0]);
  STAGE(baseB[1], 0, &Bsm[0][1][0]);
  STAGE(baseA[1], 0, &Asm[0][1][0]);
  STAGE(baseA[0], 1, &Asm[1][0][0]);
  STAGE(baseB[0], 1, &Bsm[1][0][0]);
  STAGE(baseB[1], 1, &Bsm[1][1][0]);
  asm volatile("s_waitcnt vmcnt(6)" ::: "memory");
  __builtin_amdgcn_s_barrier();

  // ---- main loop (iters 0..NT/2-2, branch-free) ----
  for (int i = 0; i < NT / 2 - 1; i++) {
    const int t1 = 2 * i + 1, t2 = 2 * i + 2, t3 = 2 * i + 3;

    // p1: (mh0, nh0) of buf0; bA <- B0.Bh0 (held through p4)
    LDA(&Asm[0][0][0], a); LDB(&Bsm[0][0][0], bA);
    STAGE(baseA[1], t1, &Asm[1][1][0]);
    PH_SYNC_MFMA(0, 0, bA);
    __builtin_amdgcn_s_barrier();
    // p2: (mh0, nh1); bB <- B0.Bh1
    LDB(&Bsm[0][1][0], bB);
    STAGE(baseA[0], t2, &Asm[0][0][0]);
    PH_SYNC_MFMA(0, 2, bB);
    __builtin_amdgcn_s_barrier();
    // p3: (mh1, nh1)
    LDA(&Asm[0][1][0], a);
    STAGE(baseB[0], t2, &Bsm[0][0][0]);
    PH_SYNC_MFMA(4, 2, bB);
    __builtin_amdgcn_s_barrier();
    // p4: (mh1, nh0) — pure registers + counted vmcnt
    STAGE(baseB[1], t2, &Bsm[0][1][0]);
    PH_SYNC_MFMA(4, 0, bA);
    asm volatile("s_waitcnt vmcnt(6)" ::: "memory");
    __builtin_amdgcn_s_barrier();
    // p5: (mh0, nh0) of buf1
    LDA(&Asm[1][0][0], a); LDB(&Bsm[1][0][0], bA);
    STAGE(baseA[1], t2, &Asm[0][1][0]);
    PH_SYNC_MFMA(0, 0, bA);
    __builtin_amdgcn_s_barrier();
    // p6: (mh0, nh1)
    LDB(&Bsm[1][1][0], bB);
    STAGE(baseA[0], t3, &Asm[1][0][0]);
    PH_SYNC_MFMA(0, 2, bB);
    __builtin_amdgcn_s_barrier();
    // p7: (mh1, nh1)
    LDA(&Asm[1][1][0], a);
    STAGE(baseB[0], t3, &Bsm[1][0][0]);
    PH_SYNC_MFMA(4, 2, bB);
    __builtin_amdgcn_s_barrier();
    // p8: (mh1, nh0) — pure registers + counted vmcnt
    STAGE(baseB[1], t3, &Bsm[1][1][0]);
    PH_SYNC_MFMA(4, 0, bA);
    asm volatile("s_waitcnt vmcnt(6)" ::: "memory");
    __builtin_amdgcn_s_barrier();
  }

  // ---- peeled last iteration (tiles NT-2 buf0, NT-1 buf1): keeps only
  // the p1 stage (buf1.Ah1 <- NT-1); p4's vmcnt(0) drains everything. ----
  {
    // p1
    LDA(&Asm[0][0][0], a); LDB(&Bsm[0][0][0], bA);
    STAGE(baseA[1], NT - 1, &Asm[1][1][0]);
    PH_SYNC_MFMA(0, 0, bA);
    __builtin_amdgcn_s_barrier();
    // p2
    LDB(&Bsm[0][1][0], bB);
    PH_SYNC_MFMA(0, 2, bB);
    __builtin_amdgcn_s_barrier();
    // p3
    LDA(&Asm[0][1][0], a);
    PH_SYNC_MFMA(4, 2, bB);
    __builtin_amdgcn_s_barrier();
    // p4 + full drain
    PH_SYNC_MFMA(4, 0, bA);
    asm volatile("s_waitcnt vmcnt(0)" ::: "memory");
    __builtin_amdgcn_s_barrier();
    // p5
    LDA(&Asm[1][0][0], a); LDB(&Bsm[1][0][0], bA);
    PH_SYNC_MFMA(0, 0, bA);
    __builtin_amdgcn_s_barrier();
    // p6
    LDB(&Bsm[1][1][0], bB);
    PH_SYNC_MFMA(0, 2, bB);
    __builtin_amdgcn_s_barrier();
    // p7
    LDA(&Asm[1][1][0], a);
    PH_SYNC_MFMA(4, 2, bB);
    __builtin_amdgcn_s_barrier();
    // p8
    PH_SYNC_MFMA(4, 0, bA);
  }

  // ---- epilogue: + bias, * mask, store f32 ----
  const int comp = tcol0 >> 10;
  const float* __restrict__ bcn = bc + (size_t)comp * DCOMP + (tcol0 & (DCOMP - 1));
  float bias[4];
#pragma unroll
  for (int n = 0; n < 4; n++)
    bias[n] = bcn[((n >> 1) * 128) + wn * 32 + (n & 1) * 16 + fr];
#pragma unroll
  for (int m = 0; m < 8; m++) {
    int growb = trow0 + ((m >> 2) * 128) + wm * 64 + (m & 3) * 16 + fq * 4;
#pragma unroll
    for (int j = 0; j < 4; j++) {
      int r = growb + j;
      float mval = G[(size_t)r * NCOMP + comp];
      float* Erow = E + (size_t)r * NOUT + tcol0;
#pragma unroll
      for (int n = 0; n < 4; n++) {
        int coll = ((n >> 1) * 128) + wn * 32 + (n & 1) * 16 + fr;
        Erow[coll] = mval * (acc[m][n][j] + bias[n]);
      }
    }
  }
}

extern "C" void kernel_launch(void* const* d_in, const int* in_sizes, int n_in,
                              void* d_out, int out_size, void* d_ws, size_t ws_size,
                              hipStream_t stream) {
  const float* x     = (const float*)d_in[0];
  const float* noise = (const float*)d_in[1];
  const float* Wc    = (const float*)d_in[2];
  const float* bc    = (const float*)d_in[3];
  const float* Wg    = (const float*)d_in[4];
  const float* bg    = (const float*)d_in[5];
  const float* Wn    = (const float*)d_in[6];
  const float* bn    = (const float*)d_in[7];

  float* E = (float*)d_out;                          // [4096, 4096]
  float* G = (float*)d_out + (size_t)BROWS * NOUT;   // [4096, 4]

  short* xb  = (short*)d_ws;                         // 16 MB bf16
  short* WcT = xb + (size_t)BROWS * DDIM;            // 16 MB bf16

  prep_kernel<<<3072, 256, 0, stream>>>(x, noise, Wg, bg, Wn, bn, Wc, G, xb, WcT);
  gemm_kernel<<<256, 512, 0, stream>>>(xb, WcT, bc, G, E);
}